// Round 5
// baseline (69.905 us; speedup 1.0000x reference)
//
#include <hip/hip_runtime.h>
#include <math.h>

#define RR 16
#define AA 8
#define BLOCK 256

typedef float v2f __attribute__((ext_vector_type(2)));

// ws float layout (all rule-indexed data stored in c1-SORTED rule order):
//   [0..127]   M      means (c = k*8+a)
//   [128..383] Q      interleaved pairs: ws[128+2c] = K*(1/sig_big)^2,
//                     ws[128+2c+1] = K*(1/sig_small)^2   (K = 0.5*log2 e)
//   [384..399] c1s  sorted c1
//   [400..415] c2s  sorted c2
//   [416..431] c2p  c2 coefficient of the rule at c1-sorted position k
//   [432..447] q    (int) c1-sorted position of the rule at c2-sorted position k

__global__ void prep_kernel(const float* __restrict__ W,
                            const float* __restrict__ c1,
                            const float* __restrict__ c2,
                            float* __restrict__ ws) {
    __shared__ float sc1[RR], sc2[RR];
    __shared__ int sp1[RR], sp2[RR], srank1[RR];
    const int t = threadIdx.x;   // 128 threads, 1 block
    if (t < RR) { sc1[t] = c1[t]; sc2[t] = c2[t]; }
    __syncthreads();
    if (t < RR) {
        // stable rank-sort (matches jnp.argsort tie-break)
        float vi = sc1[t];
        int r1 = 0;
        #pragma unroll
        for (int j = 0; j < RR; ++j)
            r1 += (sc1[j] < vi) || (sc1[j] == vi && j < t);
        srank1[t] = r1;
        sp1[r1] = t;
        float wi = sc2[t];
        int r2 = 0;
        #pragma unroll
        for (int j = 0; j < RR; ++j)
            r2 += (sc2[j] < wi) || (sc2[j] == wi && j < t);
        sp2[r2] = t;
    }
    __syncthreads();
    if (t < RR) {
        int a1 = sp1[t];          // rule at c1-sorted position t
        int a2 = sp2[t];          // rule at c2-sorted position t
        ws[384 + t] = sc1[a1];    // c1s
        ws[400 + t] = sc2[a2];    // c2s
        ws[416 + t] = sc2[a1];    // c2p
        ((int*)ws)[432 + t] = srank1[a2];  // q[k] = rank1[p2[k]]
    }
    {
        // 128 threads: one (sorted-rule k, antecedent a) pair each
        int k = t >> 3, a = t & 7;
        int src = (sp1[k] << 3) + a;       // W offset of source rule
        float m  = W[src];
        float s1 = W[src + 1];
        float s2 = W[src + 2];
        float ib = 1.0f / fmaxf(s1, s2);   // bigger sigma -> mu_big / UU
        float is = 1.0f / fminf(s1, s2);   // smaller sigma -> mu_small / LL
        const float K = 0.72134752044448f; // 0.5 * log2(e)
        ws[t]            = m;
        ws[128 + 2 * t]     = K * ib * ib;
        ws[128 + 2 * t + 1] = K * is * is;
    }
}

__global__ __launch_bounds__(BLOCK, 6) void t2fls_main(
    const float* __restrict__ x,    // N x 8
    const float* __restrict__ ws,   // prepped uniforms (scalar loads)
    float* __restrict__ out,        // N
    int n)
{
    // d = u-l per (rule, thread); own-column access only -> no barriers.
    __shared__ float DD[RR][BLOCK];   // 16 KiB

    const int tid = threadIdx.x;
    const int gid = blockIdx.x * BLOCK + tid;
    if (gid >= n) return;

    const float* pm  = ws;
    const v2f*   pq  = (const v2f*)(ws + 128);   // (qb, qs) pairs
    const float* c1s = ws + 384;
    const float* c2s = ws + 400;
    const float* c2p = ws + 416;
    const int*   q   = (const int*)ws + 432;

    const float4* xp = (const float4*)(x + (size_t)gid * AA);
    float4 a0 = xp[0], a1 = xp[1];
    float xv[AA] = {a0.x, a0.y, a0.z, a0.w, a1.x, a1.y, a1.z, a1.w};

    // ---- firing: K-scaled sums of d^2; big/small packed (v_pk_fma_f32) ----
    float sb[RR], ss[RR];
    #pragma unroll
    for (int k = 0; k < RR; ++k) {
        v2f acc = {0.0f, 0.0f};
        #pragma unroll
        for (int a = 0; a < AA; ++a) {
            const int c = k * AA + a;
            float t  = xv[a] - pm[c];      // pm[c]: uniform -> SGPR
            float t2 = t * t;
            acc = __builtin_elementwise_fma((v2f){t2, t2}, pq[c], acc);
        }
        sb[k] = acc.x;
        ss[k] = acc.y;
    }

    float smin = sb[0];
    #pragma unroll
    for (int k = 1; k < RR; ++k) smin = fminf(smin, sb[k]);

    // u,l already in c1-sorted rule order; exp scale K pre-folded
    float s0 = 0.0f, t0 = 0.0f, s0r = 0.0f, t0r = 0.0f;
    float dd[RR];
    #pragma unroll
    for (int k = 0; k < RR; ++k) {
        float u = __builtin_amdgcn_exp2f(smin - sb[k]);  // scaled UU, max 1
        float l = __builtin_amdgcn_exp2f(smin - ss[k]);  // scaled LL <= u
        s0  = fmaf(c1s[k], l, s0);   t0  += l;
        s0r = fmaf(c2p[k], u, s0r);  t0r += u;
        float d = u - l;
        dd[k] = d;                   // regs for the in-order left pass
        DD[k][tid] = d;              // LDS for the permuted right pass
    }

    // ---- FUSED left (prefix-min) / right (prefix-max) passes ----
    // Trans-free cross-multiply compares (R2 form); the two serial chains
    // are independent and interleave -> ~half the exposed chain latency.
    float bnL = s0,  bdL = t0,  csL = s0,  ctL = t0;
    float bnR = s0r, bdR = t0r, csR = s0r, ctR = t0r;
    #pragma unroll
    for (int k = 0; k < RR; ++k) {
        float dl = dd[k];                 // u - l >= 0
        csL = fmaf(c1s[k], dl, csL);
        ctL += dl;
        bool bL = (csL * bdL < bnL * ctL);   // csL/ctL < bnL/bdL, denoms > 0
        bnL = bL ? csL : bnL;
        bdL = bL ? ctL : bdL;

        float dr = -DD[q[k]][tid];        // l - u  (q[k]: uniform row)
        csR = fmaf(c2s[k], dr, csR);
        ctR += dr;
        bool bR = (csR * bdR > bnR * ctR);
        bnR = bR ? csR : bnR;
        bdR = bR ? ctR : bdR;
    }

    // 0.5*(bnL/bdL + bnR/bdR) with one fast reciprocal (absmax headroom 2^-7)
    out[gid] = 0.5f * fmaf(bnL, bdR, bnR * bdL) * __builtin_amdgcn_rcpf(bdL * bdR);
}

extern "C" void kernel_launch(void* const* d_in, const int* in_sizes, int n_in,
                              void* d_out, int out_size, void* d_ws, size_t ws_size,
                              hipStream_t stream) {
    const float* x  = (const float*)d_in[0];
    const float* W  = (const float*)d_in[1];
    const float* c1 = (const float*)d_in[2];
    const float* c2 = (const float*)d_in[3];
    float* out = (float*)d_out;
    float* ws  = (float*)d_ws;
    const int n = out_size;   // 262144

    hipLaunchKernelGGL(prep_kernel, dim3(1), dim3(128), 0, stream, W, c1, c2, ws);

    const int blocks = (n + BLOCK - 1) / BLOCK;   // 1024
    hipLaunchKernelGGL(t2fls_main, dim3(blocks), dim3(BLOCK), 0, stream,
                       x, ws, out, n);
}

// Round 6
// 67.063 us; speedup vs baseline: 1.0424x; 1.0424x over previous
//
#include <hip/hip_runtime.h>
#include <math.h>

#define RR 16
#define AA 8
#define BLOCK 256

// Single fused kernel: per-block prep (rank-sort + sigma precompute) in LDS,
// then the firing/exp/pass pipeline. No ws dependency, no prep launch.
__global__ __launch_bounds__(BLOCK, 4) void t2fls_fused(
    const float* __restrict__ x,    // N x 8
    const float* __restrict__ W,    // 3*R*A (only [0..129] referenced)
    const float* __restrict__ c1,   // 16
    const float* __restrict__ c2,   // 16
    float* __restrict__ out,        // N
    int n)
{
    __shared__ float  DD[RR][BLOCK];    // 16 KiB; rows in c1-sorted order
    __shared__ float2 PQ[RR * AA];      // 1 KiB: (K*ib^2, K*is^2) per (r,a)
    __shared__ float  C1S[RR], C2S[RR]; // sorted c1 / sorted c2
    __shared__ int    Qrow[RR];         // c1-rank of rule at c2-sorted pos k
    __shared__ int    RK1[RR], SP2[RR];

    const int tid = threadIdx.x;
    const int gid = blockIdx.x * BLOCK + tid;

    // x loads first: independent of LDS prep -> latency hides under it
    const float4* xp = (const float4*)(x + (size_t)gid * AA);
    float4 a0 = xp[0], a1 = xp[1];
    float xv[AA] = {a0.x, a0.y, a0.z, a0.w, a1.x, a1.y, a1.z, a1.w};

    // ---- block-local prep ----
    if (tid < RR) {
        float vi = c1[tid], wi = c2[tid];
        int r1 = 0, r2 = 0;
        #pragma unroll
        for (int j = 0; j < RR; ++j) {
            float uj = c1[j], vj = c2[j];      // uniform -> s_load
            r1 += (uj < vi) || (uj == vi && j < tid);   // stable argsort rank
            r2 += (vj < wi) || (vj == wi && j < tid);
        }
        RK1[tid] = r1; SP2[r2] = tid;
        C1S[r1] = vi;  C2S[r2] = wi;
    }
    if (tid < RR * AA) {
        float s1 = W[tid + 1], s2 = W[tid + 2];
        float ib = 1.0f / fmaxf(s1, s2);   // bigger sigma -> mu_big / UU
        float is = 1.0f / fminf(s1, s2);   // smaller sigma -> mu_small / LL
        const float K = 0.72134752044448f; // 0.5 * log2(e)
        PQ[tid] = make_float2(K * ib * ib, K * is * is);
    }
    __syncthreads();
    if (tid < RR) Qrow[tid] = RK1[SP2[tid]];
    __syncthreads();

    // ---- firing: K-scaled sums of d^2 (unsorted rule order) ----
    float sb[RR], ss[RR];
    #pragma unroll
    for (int r = 0; r < RR; ++r) {
        const float4* pq4 = (const float4*)(&PQ[r * AA]);  // broadcast b128
        float4 p01 = pq4[0], p23 = pq4[1], p45 = pq4[2], p67 = pq4[3];
        float qb[AA] = {p01.x, p01.z, p23.x, p23.z, p45.x, p45.z, p67.x, p67.z};
        float qs[AA] = {p01.y, p01.w, p23.y, p23.w, p45.y, p45.w, p67.y, p67.w};
        float accb = 0.0f, accs = 0.0f;
        #pragma unroll
        for (int a = 0; a < AA; ++a) {
            float t  = xv[a] - W[r * AA + a];   // W: uniform -> SGPR
            float t2 = t * t;
            accb = fmaf(t2, qb[a], accb);
            accs = fmaf(t2, qs[a], accs);
        }
        sb[r] = accb;
        ss[r] = accs;
    }

    float smin = sb[0];
    #pragma unroll
    for (int r = 1; r < RR; ++r) smin = fminf(smin, sb[r]);

    // ---- exp + order-independent sums; DD written in c1-sorted rows ----
    float s0 = 0.0f, t0 = 0.0f, s0r = 0.0f, t0r = 0.0f;
    #pragma unroll
    for (int r = 0; r < RR; ++r) {
        float u = __builtin_amdgcn_exp2f(smin - sb[r]);  // scaled UU, max 1
        float l = __builtin_amdgcn_exp2f(smin - ss[r]);  // scaled LL <= u
        s0  = fmaf(c1[r], l, s0);   t0  += l;    // unsorted coeffs: s_load
        s0r = fmaf(c2[r], u, s0r);  t0r += u;
        DD[RK1[r]][tid] = u - l;     // own column only -> no barrier
    }

    // ---- LEFT: prefix-min of ratios, rows 0..15 in order ----
    float bn = s0, bd = t0, cs = s0, ct = t0;
    #pragma unroll
    for (int k = 0; k < RR; ++k) {
        float dl = DD[k][tid];
        cs = fmaf(C1S[k], dl, cs);        // C1S: broadcast LDS -> VGPR fma
        ct += dl;
        bool bet = (cs * bd < bn * ct);   // cs/ct < bn/bd, denoms > 0
        bn = bet ? cs : bn;
        bd = bet ? ct : bd;
    }
    const float lnum = bn, lden = bd;

    // ---- RIGHT: prefix-max in c2-sorted order via permuted rows ----
    bn = s0r; bd = t0r; cs = s0r; ct = t0r;
    #pragma unroll
    for (int k = 0; k < RR; ++k) {
        float dr = -DD[Qrow[k]][tid];     // l - u  (Qrow[k]: broadcast row)
        cs = fmaf(C2S[k], dr, cs);
        ct += dr;
        bool bet = (cs * bd > bn * ct);
        bn = bet ? cs : bn;
        bd = bet ? ct : bd;
    }

    // 0.5*(lnum/lden + bn/bd), one fast reciprocal (absmax headroom 2^-7)
    if (gid < n)
        out[gid] = 0.5f * fmaf(lnum, bd, bn * lden)
                        * __builtin_amdgcn_rcpf(lden * bd);
}

extern "C" void kernel_launch(void* const* d_in, const int* in_sizes, int n_in,
                              void* d_out, int out_size, void* d_ws, size_t ws_size,
                              hipStream_t stream) {
    const float* x  = (const float*)d_in[0];
    const float* W  = (const float*)d_in[1];
    const float* c1 = (const float*)d_in[2];
    const float* c2 = (const float*)d_in[3];
    float* out = (float*)d_out;
    const int n = out_size;   // 262144

    const int blocks = (n + BLOCK - 1) / BLOCK;   // 1024
    hipLaunchKernelGGL(t2fls_fused, dim3(blocks), dim3(BLOCK), 0, stream,
                       x, W, c1, c2, out, n);
}